// Round 3
// baseline (392.466 us; speedup 1.0000x reference)
//
#include <hip/hip_runtime.h>

// ---------------------------------------------------------------------------
// SpatialAwareSelfAttention  (B=16, H=W=56, C=512, heads=8, window=4x4)
//
// Round 6: 2-phase double-buffered k_fused (T3-minimum schedule).
//   k_fused: grid (392,8) x 512 thr. Block = 128 tokens x 1 head.
//   LDS double-buffer (2 x [A 128x64 | B 192x64] = 80 KB, 2 blocks/CU):
//   per BK=64 chunk: stage(next buf) -> ds_read+MFMA(cur buf) -> ONE
//   barrier (auto vmcnt0+lgkm0). Stage latency hides under 24 MFMAs/wave.
//   Wave tile M64xN48 (Mf4 x Nf3), both-sides XOR swizzle (proven R5).
//   Attention epilogue duplicated per 64-token half (2 aliased sets).
//   k_gemm_proj: same 1-barrier dbuf conversion (64 KB, 2 blocks/CU).
// ---------------------------------------------------------------------------

using bf16x8 = __attribute__((ext_vector_type(8))) short;
using f32x4  = __attribute__((ext_vector_type(4))) float;

#define SCALE 0.044194173824159216f   // 512^-0.5 (full C, per reference)

__device__ __forceinline__ unsigned short f2bf(float f) {
    union { float f; unsigned u; } v; v.f = f;
    unsigned u = v.u;
    return (unsigned short)((u + 0x7fffu + ((u >> 16) & 1u)) >> 16);
}

__device__ __forceinline__ void gl2lds16(const unsigned short* g, unsigned short* l) {
    __builtin_amdgcn_global_load_lds(
        (const __attribute__((address_space(1))) void*)g,
        (__attribute__((address_space(3))) void*)l, 16, 0, 0);
}

// ---- K0a: weight conversion/repack ----------------------------------------
__global__ void k_prep_weights(const float* __restrict__ wqkv_h,
                               const float* __restrict__ wqkv_l,
                               const float* __restrict__ wproj,
                               unsigned short* __restrict__ WH,
                               unsigned short* __restrict__ WLV,
                               unsigned short* __restrict__ WP1,
                               unsigned short* __restrict__ WP2) {
    int i = blockIdx.x * 256 + threadIdx.x;
    if (i < 786432) {
        WH[i] = f2bf(wqkv_h[i]);              // [1536][512] row-major
    } else {
        int j = i - 786432;
        int r = j >> 18;
        int t = j & 262143;
        int n = t >> 9, k = t & 511;
        if (r == 0)      WLV[t] = f2bf(wqkv_l[(1024 + n) * 512 + k]); // v-rows
        else if (r == 1) WP1[t] = f2bf(wproj[n * 1024 + k]);
        else             WP2[t] = f2bf(wproj[n * 1024 + 512 + k]);
    }
}

// ---- K0b: window partition + pooling (float4 / ushort4) -------------------
__global__ void k_window_pool(const float* __restrict__ x,
                              unsigned short* __restrict__ XW,
                              unsigned short* __restrict__ XAVG) {
    int win = blockIdx.x * 2 + (threadIdx.x >> 7);
    int g = threadIdx.x & 127;
    int c = g * 4;
    int b = win / 196, rem = win % 196, wh = rem / 14, ww = rem % 14;
    float4 s = {0.f, 0.f, 0.f, 0.f};
    #pragma unroll
    for (int t = 0; t < 16; ++t) {
        int row = (b * 56 + wh * 4 + (t >> 2)) * 56 + ww * 4 + (t & 3);
        float4 v = *(const float4*)&x[(size_t)row * 512 + c];
        uint2 pk;
        pk.x = (unsigned)f2bf(v.x) | ((unsigned)f2bf(v.y) << 16);
        pk.y = (unsigned)f2bf(v.z) | ((unsigned)f2bf(v.w) << 16);
        *(uint2*)&XW[(size_t)(win * 16 + t) * 512 + c] = pk;
        s.x += v.x; s.y += v.y; s.z += v.z; s.w += v.w;
    }
    uint2 pa;
    pa.x = (unsigned)f2bf(s.x * 0.0625f) | ((unsigned)f2bf(s.y * 0.0625f) << 16);
    pa.y = (unsigned)f2bf(s.z * 0.0625f) | ((unsigned)f2bf(s.w * 0.0625f) << 16);
    *(uint2*)&XAVG[(size_t)win * 512 + c] = pa;
}

// ---- K1: small K=512 GEMM C = A @ B^T, wave tile 16 x (NT*16) -------------
template <int NT>
__global__ void k_gemm512(const unsigned short* __restrict__ A,
                          const unsigned short* __restrict__ Bw,
                          unsigned short* __restrict__ outB,
                          float* __restrict__ outF,
                          const float* __restrict__ bias) {
    int wave = threadIdx.x >> 6, lane = threadIdx.x & 63;
    int quad = lane >> 4, l16 = lane & 15;
    int m0 = blockIdx.x * 64 + wave * 16;
    int n0 = blockIdx.y * (NT * 16);
    f32x4 acc[NT] = {};
    const unsigned short* arow = A + (size_t)(m0 + l16) * 512 + quad * 8;
    for (int kk = 0; kk < 16; ++kk) {
        bf16x8 a = *(const bf16x8*)(arow + kk * 32);
        #pragma unroll
        for (int nt = 0; nt < NT; ++nt) {
            bf16x8 b = *(const bf16x8*)(Bw + (size_t)(n0 + nt * 16 + l16) * 512 + kk * 32 + quad * 8);
            acc[nt] = __builtin_amdgcn_mfma_f32_16x16x32_bf16(a, b, acc[nt], 0, 0, 0);
        }
    }
    #pragma unroll
    for (int nt = 0; nt < NT; ++nt) {
        int col = n0 + nt * 16 + l16;
        float bv = (bias != nullptr) ? bias[col] : 0.f;
        #pragma unroll
        for (int r = 0; r < 4; ++r) {
            int row = m0 + quad * 4 + r;
            if (outF != nullptr) outF[(size_t)row * 512 + col] = acc[nt][r] + bv;
            else                 outB[(size_t)row * 512 + col] = f2bf(acc[nt][r]);
        }
    }
}

// ---- K2: fused qkv GEMM (128x192x512) + window attention ------------------
// grid (392, 8) XCD-remapped; 512 threads. Block = 128 tokens x 1 head.
// Double-buffered BK=64 chunks, ONE barrier per chunk (stage overlaps MFMA).
// Wave grid: mh = wave>>2 (M-half 0/1), nq = wave&3 (N-quarter of 192 cols).
__global__ void __launch_bounds__(512, 4) k_fused(const unsigned short* __restrict__ XW,
                                                  const unsigned short* __restrict__ WH,
                                                  unsigned short* __restrict__ XH) {
    __shared__ __align__(16) char smem[81920];
    // staging double-buffer: buf b at b*40960: A [128][64] 16384 B, B [192][64] 24576 B
    // attention sets (alias staging, used after K-loop): set s at s*33792:
    //   qs [64][72] 9216 | ks [64][72] 9216 | vts [64][88] 11264 | Ps [4][16][32] 4096

    const int tid  = threadIdx.x;
    const int wave = tid >> 6, lane = tid & 63;
    const int quad = lane >> 4, l16 = lane & 15;
    const int mh = wave >> 2, nq = wave & 3;

    // bijective XCD remap (3136 = 8*392): XCD c gets token-superblocks
    // [c*49, c*49+49), heads cycling fastest -> A-tile + whole-WH L2 reuse.
    int id   = blockIdx.y * 392 + blockIdx.x;
    int s_   = id >> 3;
    int tb   = (id & 7) * 49 + (s_ >> 3);
    int head = s_ & 7;
    const int m0 = tb * 128;

    // ---- staging maps (rule #21: linear gl2lds dest, inverse-swizzled
    //      global src, swizzled ds_read). Rows are 64 shorts = 8 16B-units;
    //      stored unit u holds global unit u^(row&7).
    size_t aof[2];
    #pragma unroll
    for (int i = 0; i < 2; ++i) {
        int u = i * 512 + tid;                 // A unit 0..1023
        int n = u >> 3;                        // A row 0..127
        int gu = (u & 7) ^ (n & 7);
        aof[i] = (size_t)(m0 + n) * 512 + gu * 8;
    }
    size_t bof[3];
    #pragma unroll
    for (int i = 0; i < 3; ++i) {
        int u = i * 512 + tid;                 // B unit 0..1535
        int n = u >> 3;                        // qkv row 0..191 (s-major)
        int gu = (u & 7) ^ (n & 7);
        int nrow = (n >> 6) * 512 + head * 64 + (n & 63);
        bof[i] = (size_t)nrow * 512 + gu * 8;
    }

    unsigned short* const bufA[2] = { (unsigned short*)smem,
                                      (unsigned short*)(smem + 40960) };
    unsigned short* const bufB[2] = { (unsigned short*)(smem + 16384),
                                      (unsigned short*)(smem + 40960 + 16384) };

    f32x4 acc[4][3] = {};    // [Mfrag][Nfrag]: rows mh*64+mf*16+, cols nq*48+j*16+
    const int sx = l16 & 7;

    // prologue: stage chunk 0 -> buf0
    #pragma unroll
    for (int i = 0; i < 2; ++i)
        gl2lds16(XW + aof[i], bufA[0] + (i * 512 + wave * 64) * 8);
    #pragma unroll
    for (int i = 0; i < 3; ++i)
        gl2lds16(WH + bof[i], bufB[0] + (i * 512 + wave * 64) * 8);
    __syncthreads();                            // vmcnt(0) auto: chunk 0 ready

    #pragma unroll
    for (int ch = 0; ch < 8; ++ch) {
        unsigned short* As = bufA[ch & 1];
        unsigned short* Bs = bufB[ch & 1];
        if (ch < 7) {                           // stage next chunk -> other buf
            unsigned short* An = bufA[(ch + 1) & 1];
            unsigned short* Bn = bufB[(ch + 1) & 1];
            #pragma unroll
            for (int i = 0; i < 2; ++i)
                gl2lds16(XW + aof[i] + (ch + 1) * 64, An + (i * 512 + wave * 64) * 8);
            #pragma unroll
            for (int i = 0; i < 3; ++i)
                gl2lds16(WH + bof[i] + (ch + 1) * 64, Bn + (i * 512 + wave * 64) * 8);
        }
        #pragma unroll
        for (int kk = 0; kk < 2; ++kk) {        // compute current chunk
            int su = ((kk * 4 + quad) ^ sx) * 8;
            bf16x8 a[4], b[3];
            #pragma unroll
            for (int mf = 0; mf < 4; ++mf) {
                int row = mh * 64 + mf * 16 + l16;
                a[mf] = *(const bf16x8*)&As[row * 64 + (((kk * 4 + quad) ^ (row & 7)) ^ sx ^ (row & 7)) * 8];
            }
            #pragma unroll
            for (int j = 0; j < 3; ++j) {
                int brow = nq * 48 + j * 16 + l16;
                b[j] = *(const bf16x8*)&Bs[brow * 64 + (((kk * 4 + quad) ^ (brow & 7)) ^ sx ^ (brow & 7)) * 8];
            }
            #pragma unroll
            for (int mf = 0; mf < 4; ++mf)
                #pragma unroll
                for (int j = 0; j < 3; ++j)
                    acc[mf][j] = __builtin_amdgcn_mfma_f32_16x16x32_bf16(a[mf], b[j], acc[mf][j], 0, 0, 0);
        }
        __syncthreads();   // ONE barrier: drains stage (vmcnt0) + all reads done
    }
    // NOTE on the swizzle expression above: stored unit for global unit g at
    // row n is g^(n&7); lanes read g = kk*4+quad. The expression folds to
    // ((kk*4+quad)^(row&7)) — the ^sx^(row&7) pair cancels sx only when
    // row&7 == l16&7 (true: row = base16*k + l16 with base multiple of 16,
    // so row&7 == l16&7 == sx). Kept explicit for clarity; compiler folds.

    // ---- scatter q/k/v^T into attention LDS (aliases staging) -------------
    {
        char* att = smem + mh * 33792;
        unsigned short* qs  = (unsigned short*)att;
        unsigned short* ks  = (unsigned short*)(att + 9216);
        unsigned short* vts = (unsigned short*)(att + 18432);
        #pragma unroll
        for (int j = 0; j < 3; ++j) {
            int cb = nq * 48 + j * 16;          // 16-aligned col-block in 0..191
            #pragma unroll
            for (int mf = 0; mf < 4; ++mf) {
                #pragma unroll
                for (int r = 0; r < 4; ++r) {
                    int tok = mf * 16 + quad * 4 + r;   // set-local token 0..63
                    unsigned short hv = f2bf(acc[mf][j][r]);
                    if (cb < 64)       qs[tok * 72 + cb + l16] = hv;
                    else if (cb < 128) ks[tok * 72 + (cb - 64) + l16] = hv;
                    else               vts[(cb - 128 + l16) * 88 + tok] = hv;
                }
            }
        }
    }
    __syncthreads();

    // attention set for THIS wave:
    char* att = smem + (wave >> 2) * 33792;
    unsigned short* qs  = (unsigned short*)att;
    unsigned short* ks  = (unsigned short*)(att + 9216);
    unsigned short* vts = (unsigned short*)(att + 18432);
    unsigned short* Ps  = (unsigned short*)(att + 29696);
    const int lw = wave & 3, t0 = lw * 16;

    // re-zero pads (wave-local consumers; no barrier needed):
    // vts token-cols 64..79 (lw==3's PV K-pad), Ps cols 16..31.
    if (lw == 3) {
        #pragma unroll
        for (int i = 0; i < 16; ++i) vts[lane * 88 + 64 + i] = 0;
    }
    {
        int prow = lane >> 2, pc = 16 + (lane & 3) * 4;
        #pragma unroll
        for (int i = 0; i < 4; ++i) Ps[lw * 512 + prow * 32 + pc + i] = 0;
    }

    // ---- S = (q @ k^T) * scale --------------------------------------------
    f32x4 sacc = {};
    {
        bf16x8 a0 = *(const bf16x8*)&qs[(t0 + l16) * 72 + quad * 8];
        bf16x8 b0 = *(const bf16x8*)&ks[(t0 + l16) * 72 + quad * 8];
        sacc = __builtin_amdgcn_mfma_f32_16x16x32_bf16(a0, b0, sacc, 0, 0, 0);
        bf16x8 a1 = *(const bf16x8*)&qs[(t0 + l16) * 72 + 32 + quad * 8];
        bf16x8 b1 = *(const bf16x8*)&ks[(t0 + l16) * 72 + 32 + quad * 8];
        sacc = __builtin_amdgcn_mfma_f32_16x16x32_bf16(a1, b1, sacc, 0, 0, 0);
    }
    // ---- in-register softmax: row r lives across the quad's 16 lanes ------
    float p[4];
    #pragma unroll
    for (int r = 0; r < 4; ++r) {
        float v = sacc[r] * SCALE;
        float m = v;
        m = fmaxf(m, __shfl_xor(m, 1));
        m = fmaxf(m, __shfl_xor(m, 2));
        m = fmaxf(m, __shfl_xor(m, 4));
        m = fmaxf(m, __shfl_xor(m, 8));
        float e = __expf(v - m);
        float sm = e;
        sm += __shfl_xor(sm, 1);
        sm += __shfl_xor(sm, 2);
        sm += __shfl_xor(sm, 4);
        sm += __shfl_xor(sm, 8);
        p[r] = e / sm;
    }
    #pragma unroll
    for (int r = 0; r < 4; ++r)
        Ps[lw * 512 + (quad * 4 + r) * 32 + l16] = f2bf(p[r]);

    // ---- y = P @ v (K=16 padded to 32; pad-P is zero) ---------------------
    bf16x8 pa = *(const bf16x8*)&Ps[lw * 512 + l16 * 32 + quad * 8];
    #pragma unroll
    for (int nt = 0; nt < 4; ++nt) {
        f32x4 y = {};
        bf16x8 bv = *(const bf16x8*)&vts[(nt * 16 + l16) * 88 + t0 + quad * 8];
        y = __builtin_amdgcn_mfma_f32_16x16x32_bf16(pa, bv, y, 0, 0, 0);
        #pragma unroll
        for (int r = 0; r < 4; ++r)
            XH[(size_t)(m0 + (wave >> 2) * 64 + t0 + quad * 4 + r) * 512 + head * 64 + nt * 16 + l16] = f2bf(y[r]);
    }
}

// ---- K3: out = XH @ WP1^T + G[win], 128x128 block, wave 64x64, dbuf -------
// grid (392, 4), XCD-remapped; BK=64 double-buffered, 1 barrier/chunk.
__global__ void __launch_bounds__(256, 2) k_gemm_proj(const unsigned short* __restrict__ XH,
                                                      const unsigned short* __restrict__ WP1,
                                                      const float* __restrict__ G,
                                                      float* __restrict__ out) {
    __shared__ __align__(16) char smem[65536];   // 2 x (A 16KB | B 16KB)

    const int wave = threadIdx.x >> 6, lane = threadIdx.x & 63;
    const int quad = lane >> 4, l16 = lane & 15;

    // bijective XCD remap (1568 = 8*196)
    int id = blockIdx.y * 392 + blockIdx.x;
    int s  = id >> 3;
    int xb = (id & 7) * 49 + (s >> 2);
    int yb = s & 3;
    const int m0 = xb * 128, n0 = yb * 128;
    const int wm = (wave >> 1) * 64;   // wave row offset (2x2 wave grid)
    const int wn = (wave & 1) * 64;    // wave col offset

    size_t aofs[4], bofs[4];
    #pragma unroll
    for (int i = 0; i < 4; ++i) {
        int u = (wave * 4 + i) * 64 + lane;   // unit 0..1023
        int n = u >> 3;                        // row 0..127
        int gu = (lane & 7) ^ (n & 7);
        aofs[i] = (size_t)(m0 + n) * 512 + gu * 8;
        bofs[i] = (size_t)(n0 + n) * 512 + gu * 8;
    }

    unsigned short* const bufA[2] = { (unsigned short*)smem,
                                      (unsigned short*)(smem + 32768) };
    unsigned short* const bufB[2] = { (unsigned short*)(smem + 16384),
                                      (unsigned short*)(smem + 32768 + 16384) };

    f32x4 acc[4][4] = {};
    const int sx = l16 & 7;

    // prologue: stage chunk 0 -> buf0
    #pragma unroll
    for (int i = 0; i < 4; ++i) {
        gl2lds16(XH + aofs[i], bufA[0] + (wave * 4 + i) * 512);
        gl2lds16(WP1 + bofs[i], bufB[0] + (wave * 4 + i) * 512);
    }
    __syncthreads();

    #pragma unroll
    for (int ch = 0; ch < 8; ++ch) {
        unsigned short* As = bufA[ch & 1];
        unsigned short* Bs = bufB[ch & 1];
        if (ch < 7) {
            unsigned short* An = bufA[(ch + 1) & 1];
            unsigned short* Bn = bufB[(ch + 1) & 1];
            #pragma unroll
            for (int i = 0; i < 4; ++i) {
                gl2lds16(XH + aofs[i] + (ch + 1) * 64, An + (wave * 4 + i) * 512);
                gl2lds16(WP1 + bofs[i] + (ch + 1) * 64, Bn + (wave * 4 + i) * 512);
            }
        }
        #pragma unroll
        for (int kk = 0; kk < 2; ++kk) {
            int su = ((kk * 4 + quad) ^ sx) * 8;
            bf16x8 a[4], b[4];
            #pragma unroll
            for (int mf = 0; mf < 4; ++mf)
                a[mf] = *(const bf16x8*)&As[(wm + mf * 16 + l16) * 64 + su];
            #pragma unroll
            for (int j = 0; j < 4; ++j)
                b[j] = *(const bf16x8*)&Bs[(wn + j * 16 + l16) * 64 + su];
            #pragma unroll
            for (int mf = 0; mf < 4; ++mf)
                #pragma unroll
                for (int j = 0; j < 4; ++j)
                    acc[mf][j] = __builtin_amdgcn_mfma_f32_16x16x32_bf16(a[mf], b[j], acc[mf][j], 0, 0, 0);
        }
        __syncthreads();   // one barrier: stage drained + reads done
    }

    #pragma unroll
    for (int mf = 0; mf < 4; ++mf) {
        #pragma unroll
        for (int r = 0; r < 4; ++r) {
            int tl  = wm + mf * 16 + quad * 4 + r;   // 0..127
            int gt  = m0 + tl;                        // global token
            int win = gt >> 4, tw = gt & 15;
            int bb = win / 196, rem = win % 196;
            int wh = rem / 14, ww = rem % 14;
            int orow = (bb * 56 + wh * 4 + (tw >> 2)) * 56 + ww * 4 + (tw & 3);
            #pragma unroll
            for (int j = 0; j < 4; ++j) {
                int ncol = n0 + wn + j * 16 + l16;
                out[(size_t)orow * 512 + ncol] = acc[mf][j][r] + G[(size_t)win * 512 + ncol];
            }
        }
    }
}

// ---------------------------------------------------------------------------
extern "C" void kernel_launch(void* const* d_in, const int* in_sizes, int n_in,
                              void* d_out, int out_size, void* d_ws, size_t ws_size,
                              hipStream_t stream) {
    const float* x      = (const float*)d_in[0];
    const float* wqkv_h = (const float*)d_in[1];
    const float* wqkv_l = (const float*)d_in[2];
    const float* wproj  = (const float*)d_in[3];
    const float* bproj  = (const float*)d_in[4];
    float* out = (float*)d_out;

    char* ws = (char*)d_ws;
    unsigned short* WH   = (unsigned short*)(ws + 0);         // 1536*512 bf16
    unsigned short* WLV  = (unsigned short*)(ws + 1572864);   // 512*512
    unsigned short* WP1  = (unsigned short*)(ws + 2097152);   // 512*512
    unsigned short* WP2  = (unsigned short*)(ws + 2621440);   // 512*512
    unsigned short* XW   = (unsigned short*)(ws + 3145728);   // 50176*512
    unsigned short* XAVG = (unsigned short*)(ws + 54525952);  // 3136*512
    unsigned short* VL   = (unsigned short*)(ws + 57737216);  // 3136*512
    float*          G    = (float*)(ws + 60948480);           // 3136*512 f32
    unsigned short* XH   = (unsigned short*)(ws + 67371008);  // 50176*512

    k_prep_weights<<<dim3(6144), dim3(256), 0, stream>>>(wqkv_h, wqkv_l, wproj, WH, WLV, WP1, WP2);
    k_window_pool<<<dim3(1568), dim3(256), 0, stream>>>(x, XW, XAVG);
    k_gemm512<2><<<dim3(49, 16), dim3(256), 0, stream>>>(XAVG, WLV, VL, (float*)nullptr, (const float*)nullptr);
    k_gemm512<2><<<dim3(49, 16), dim3(256), 0, stream>>>(VL, WP2, (unsigned short*)nullptr, G, bproj);
    k_fused<<<dim3(392, 8), dim3(512), 0, stream>>>(XW, WH, XH);
    k_gemm_proj<<<dim3(392, 4), dim3(256), 0, stream>>>(XH, WP1, G, out);
}

// Round 5
// 390.276 us; speedup vs baseline: 1.0056x; 1.0056x over previous
//
#include <hip/hip_runtime.h>

// ---------------------------------------------------------------------------
// SpatialAwareSelfAttention  (B=16, H=W=56, C=512, heads=8, window=4x4)
//
// Round 8: R7 design (LDS-read-BW attack), hardened after container failure:
//   - static LDS cut 135168 -> 131072 B (verified-working 128 KiB size):
//     vts stride 88 -> 80, attention set = 32768 B.
//   - barrier idiom: asm s_waitcnt + __builtin_amdgcn_s_barrier() (verified
//     m201 pattern) instead of raw s_barrier inside asm.
// Design: k_fused grid (196,8) x 512 thr; block = 256 tokens x 1 head.
//   8 waves of M64 x N96 (Mf4 x Nf6, 96-VGPR acc): 10 ds_read_b128 per
//   24 MFMAs (R6 was 7 per 12) -> -29% LDS bytes/FLOP (R6 was LDS-read
//   bound at 26% MfmaUtil = measured ceiling). Counted-vmcnt dbuf (T4):
//   stage(ch+1)'s 7 loads stay in flight across both barriers, vmcnt(7)
//   retires exactly chunk ch. 1 block/CU.
// ---------------------------------------------------------------------------

using bf16x8 = __attribute__((ext_vector_type(8))) short;
using f32x4  = __attribute__((ext_vector_type(4))) float;

#define SCALE 0.044194173824159216f   // 512^-0.5 (full C, per reference)

__device__ __forceinline__ unsigned short f2bf(float f) {
    union { float f; unsigned u; } v; v.f = f;
    unsigned u = v.u;
    return (unsigned short)((u + 0x7fffu + ((u >> 16) & 1u)) >> 16);
}

__device__ __forceinline__ void gl2lds16(const unsigned short* g, unsigned short* l) {
    __builtin_amdgcn_global_load_lds(
        (const __attribute__((address_space(1))) void*)g,
        (__attribute__((address_space(3))) void*)l, 16, 0, 0);
}

// ---- K0a: weight conversion/repack ----------------------------------------
__global__ void k_prep_weights(const float* __restrict__ wqkv_h,
                               const float* __restrict__ wqkv_l,
                               const float* __restrict__ wproj,
                               unsigned short* __restrict__ WH,
                               unsigned short* __restrict__ WLV,
                               unsigned short* __restrict__ WP1,
                               unsigned short* __restrict__ WP2) {
    int i = blockIdx.x * 256 + threadIdx.x;
    if (i < 786432) {
        WH[i] = f2bf(wqkv_h[i]);              // [1536][512] row-major
    } else {
        int j = i - 786432;
        int r = j >> 18;
        int t = j & 262143;
        int n = t >> 9, k = t & 511;
        if (r == 0)      WLV[t] = f2bf(wqkv_l[(1024 + n) * 512 + k]); // v-rows
        else if (r == 1) WP1[t] = f2bf(wproj[n * 1024 + k]);
        else             WP2[t] = f2bf(wproj[n * 1024 + 512 + k]);
    }
}

// ---- K0b: window partition + pooling (float4 / ushort4) -------------------
__global__ void k_window_pool(const float* __restrict__ x,
                              unsigned short* __restrict__ XW,
                              unsigned short* __restrict__ XAVG) {
    int win = blockIdx.x * 2 + (threadIdx.x >> 7);
    int g = threadIdx.x & 127;
    int c = g * 4;
    int b = win / 196, rem = win % 196, wh = rem / 14, ww = rem % 14;
    float4 s = {0.f, 0.f, 0.f, 0.f};
    #pragma unroll
    for (int t = 0; t < 16; ++t) {
        int row = (b * 56 + wh * 4 + (t >> 2)) * 56 + ww * 4 + (t & 3);
        float4 v = *(const float4*)&x[(size_t)row * 512 + c];
        uint2 pk;
        pk.x = (unsigned)f2bf(v.x) | ((unsigned)f2bf(v.y) << 16);
        pk.y = (unsigned)f2bf(v.z) | ((unsigned)f2bf(v.w) << 16);
        *(uint2*)&XW[(size_t)(win * 16 + t) * 512 + c] = pk;
        s.x += v.x; s.y += v.y; s.z += v.z; s.w += v.w;
    }
    uint2 pa;
    pa.x = (unsigned)f2bf(s.x * 0.0625f) | ((unsigned)f2bf(s.y * 0.0625f) << 16);
    pa.y = (unsigned)f2bf(s.z * 0.0625f) | ((unsigned)f2bf(s.w * 0.0625f) << 16);
    *(uint2*)&XAVG[(size_t)win * 512 + c] = pa;
}

// ---- K1: small K=512 GEMM C = A @ B^T, wave tile 16 x (NT*16) -------------
template <int NT>
__global__ void k_gemm512(const unsigned short* __restrict__ A,
                          const unsigned short* __restrict__ Bw,
                          unsigned short* __restrict__ outB,
                          float* __restrict__ outF,
                          const float* __restrict__ bias) {
    int wave = threadIdx.x >> 6, lane = threadIdx.x & 63;
    int quad = lane >> 4, l16 = lane & 15;
    int m0 = blockIdx.x * 64 + wave * 16;
    int n0 = blockIdx.y * (NT * 16);
    f32x4 acc[NT] = {};
    const unsigned short* arow = A + (size_t)(m0 + l16) * 512 + quad * 8;
    for (int kk = 0; kk < 16; ++kk) {
        bf16x8 a = *(const bf16x8*)(arow + kk * 32);
        #pragma unroll
        for (int nt = 0; nt < NT; ++nt) {
            bf16x8 b = *(const bf16x8*)(Bw + (size_t)(n0 + nt * 16 + l16) * 512 + kk * 32 + quad * 8);
            acc[nt] = __builtin_amdgcn_mfma_f32_16x16x32_bf16(a, b, acc[nt], 0, 0, 0);
        }
    }
    #pragma unroll
    for (int nt = 0; nt < NT; ++nt) {
        int col = n0 + nt * 16 + l16;
        float bv = (bias != nullptr) ? bias[col] : 0.f;
        #pragma unroll
        for (int r = 0; r < 4; ++r) {
            int row = m0 + quad * 4 + r;
            if (outF != nullptr) outF[(size_t)row * 512 + col] = acc[nt][r] + bv;
            else                 outB[(size_t)row * 512 + col] = f2bf(acc[nt][r]);
        }
    }
}

// ---- K2: fused qkv GEMM (256x192x512) + window attention ------------------
// grid (196, 8) XCD-remapped; 512 threads, 8 waves of M64 x N96.
// mh = wave>>1 (M-quarter of 256), nq = wave&1 (N-half of 192).
// Counted-vmcnt dbuf: stage(ch+1) -> vmcnt(7)+barrier -> compute -> barrier.
__global__ void __launch_bounds__(512, 2) k_fused(const unsigned short* __restrict__ XW,
                                                  const unsigned short* __restrict__ WH,
                                                  unsigned short* __restrict__ XH) {
    __shared__ __align__(16) char smem[131072];
    // staging dbuf: buf b at b*57344: A [256][64] 32768 B, B [192][64] 24576 B
    // attention sets (alias staging, after K-loop): set s (=M-quarter) at
    // s*32768: qs [64][72] 9216 | ks [64][72] 9216 | vts [64][80] 10240 |
    // Ps [4][16][32] 4096  (= 32768 B per set, 4 sets = 131072)

    const int tid  = threadIdx.x;
    const int wave = tid >> 6, lane = tid & 63;
    const int quad = lane >> 4, l16 = lane & 15;
    const int mh = wave >> 1, nq = wave & 1;

    // bijective XCD remap (1568 = 8*196): XCD c gets contiguous work range
    // [c*196, (c+1)*196) of w = tb*8+head -> heads of a tb run on one XCD.
    int id   = blockIdx.y * 196 + blockIdx.x;
    int w_   = (id & 7) * 196 + (id >> 3);
    int tb   = w_ >> 3, head = w_ & 7;
    const int m0 = tb * 256;

    // staging maps (rule #21: linear gl2lds dest, inverse-swizzled global
    // src, swizzled ds_read). Row = 64 shorts = 8 16B-units; stored unit u
    // holds global unit (u&7)^(row&7).
    int aof[4];
    #pragma unroll
    for (int i = 0; i < 4; ++i) {
        int u = i * 512 + tid;                 // A unit 0..2047
        int n = u >> 3;                        // A row 0..255
        int gu = (u & 7) ^ (n & 7);
        aof[i] = (m0 + n) * 512 + gu * 8;
    }
    int bof[3];
    #pragma unroll
    for (int i = 0; i < 3; ++i) {
        int u = i * 512 + tid;                 // B unit 0..1535
        int n = u >> 3;                        // qkv row 0..191 (s-major)
        int gu = (u & 7) ^ (n & 7);
        int nrow = (n >> 6) * 512 + head * 64 + (n & 63);
        bof[i] = nrow * 512 + gu * 8;
    }

    f32x4 acc[4][6] = {};   // rows mh*64+mf*16+, cols nq*96+j*16+
    const int sx = l16 & 7;

    // prologue: stage chunk 0 -> buf0 (7 gl2lds/wave in flight)
    {
        unsigned short* A0 = (unsigned short*)smem;
        unsigned short* B0 = (unsigned short*)(smem + 32768);
        #pragma unroll
        for (int i = 0; i < 4; ++i) gl2lds16(XW + aof[i], A0 + (i * 512 + wave * 64) * 8);
        #pragma unroll
        for (int i = 0; i < 3; ++i) gl2lds16(WH + bof[i], B0 + (i * 512 + wave * 64) * 8);
    }

    #pragma unroll
    for (int ch = 0; ch < 8; ++ch) {
        if (ch < 7) {                          // stage next chunk -> other buf
            unsigned short* An = (unsigned short*)(smem + ((ch + 1) & 1) * 57344);
            unsigned short* Bn = (unsigned short*)(smem + ((ch + 1) & 1) * 57344 + 32768);
            #pragma unroll
            for (int i = 0; i < 4; ++i) gl2lds16(XW + aof[i] + (ch + 1) * 64, An + (i * 512 + wave * 64) * 8);
            #pragma unroll
            for (int i = 0; i < 3; ++i) gl2lds16(WH + bof[i] + (ch + 1) * 64, Bn + (i * 512 + wave * 64) * 8);
        }
        // wait for stage(ch) only — stage(ch+1)'s 7 loads stay in flight
        if (ch < 7) asm volatile("s_waitcnt vmcnt(7)" ::: "memory");
        else        asm volatile("s_waitcnt vmcnt(0)" ::: "memory");
        __builtin_amdgcn_s_barrier();

        unsigned short* As = (unsigned short*)(smem + (ch & 1) * 57344);
        unsigned short* Bs = (unsigned short*)(smem + (ch & 1) * 57344 + 32768);
        #pragma unroll
        for (int kk = 0; kk < 2; ++kk) {
            int su = ((kk * 4 + quad) ^ sx) * 8;
            bf16x8 a[4], b[6];
            #pragma unroll
            for (int mf = 0; mf < 4; ++mf)
                a[mf] = *(const bf16x8*)&As[(mh * 64 + mf * 16 + l16) * 64 + su];
            #pragma unroll
            for (int j = 0; j < 6; ++j)
                b[j] = *(const bf16x8*)&Bs[(nq * 96 + j * 16 + l16) * 64 + su];
            #pragma unroll
            for (int mf = 0; mf < 4; ++mf)
                #pragma unroll
                for (int j = 0; j < 6; ++j)
                    acc[mf][j] = __builtin_amdgcn_mfma_f32_16x16x32_bf16(a[mf], b[j], acc[mf][j], 0, 0, 0);
        }
        // all LDS reads complete before next iter's stage overwrites this buf
        asm volatile("s_waitcnt lgkmcnt(0)" ::: "memory");
        __builtin_amdgcn_s_barrier();
    }

    // ---- scatter q/k/v^T into attention LDS (aliases staging) -------------
    {
        char* att = smem + mh * 32768;
        unsigned short* qs  = (unsigned short*)att;
        unsigned short* ks  = (unsigned short*)(att + 9216);
        unsigned short* vts = (unsigned short*)(att + 18432);
        #pragma unroll
        for (int j = 0; j < 6; ++j) {
            int cb = nq * 96 + j * 16;          // 16-aligned col in 0..176
            #pragma unroll
            for (int mf = 0; mf < 4; ++mf) {
                #pragma unroll
                for (int r = 0; r < 4; ++r) {
                    int tok = mf * 16 + quad * 4 + r;   // set-local token 0..63
                    unsigned short hv = f2bf(acc[mf][j][r]);
                    if (cb < 64)       qs[tok * 72 + cb + l16] = hv;
                    else if (cb < 128) ks[tok * 72 + (cb - 64) + l16] = hv;
                    else               vts[(cb - 128 + l16) * 80 + tok] = hv;
                }
            }
        }
    }
    __syncthreads();

    // attention: wave handles windows of its own set (= M-quarter mh).
    char* att = smem + (wave >> 1) * 32768;
    unsigned short* qs  = (unsigned short*)att;
    unsigned short* ks  = (unsigned short*)(att + 9216);
    unsigned short* vts = (unsigned short*)(att + 18432);
    unsigned short* Ps  = (unsigned short*)(att + 28672);
    const int set = wave >> 1;

    #pragma unroll
    for (int sub = 0; sub < 2; ++sub) {
        const int lw = (wave & 1) * 2 + sub;    // window-in-set 0..3
        const int t0 = lw * 16;

        // re-zero pads (staging clobbered them; consumers are wave-local):
        if (lw == 3) {
            #pragma unroll
            for (int i = 0; i < 16; ++i) vts[lane * 80 + 64 + i] = 0;
        }
        {
            int prow = lane >> 2, pc = 16 + (lane & 3) * 4;
            #pragma unroll
            for (int i = 0; i < 4; ++i) Ps[lw * 512 + prow * 32 + pc + i] = 0;
        }

        // S = (q @ k^T) * scale
        f32x4 sacc = {};
        {
            bf16x8 a0 = *(const bf16x8*)&qs[(t0 + l16) * 72 + quad * 8];
            bf16x8 b0 = *(const bf16x8*)&ks[(t0 + l16) * 72 + quad * 8];
            sacc = __builtin_amdgcn_mfma_f32_16x16x32_bf16(a0, b0, sacc, 0, 0, 0);
            bf16x8 a1 = *(const bf16x8*)&qs[(t0 + l16) * 72 + 32 + quad * 8];
            bf16x8 b1 = *(const bf16x8*)&ks[(t0 + l16) * 72 + 32 + quad * 8];
            sacc = __builtin_amdgcn_mfma_f32_16x16x32_bf16(a1, b1, sacc, 0, 0, 0);
        }
        // in-register softmax: row r lives across the quad's 16 lanes
        float p[4];
        #pragma unroll
        for (int r = 0; r < 4; ++r) {
            float v = sacc[r] * SCALE;
            float m = v;
            m = fmaxf(m, __shfl_xor(m, 1));
            m = fmaxf(m, __shfl_xor(m, 2));
            m = fmaxf(m, __shfl_xor(m, 4));
            m = fmaxf(m, __shfl_xor(m, 8));
            float e = __expf(v - m);
            float sm = e;
            sm += __shfl_xor(sm, 1);
            sm += __shfl_xor(sm, 2);
            sm += __shfl_xor(sm, 4);
            sm += __shfl_xor(sm, 8);
            p[r] = e / sm;
        }
        #pragma unroll
        for (int r = 0; r < 4; ++r)
            Ps[lw * 512 + (quad * 4 + r) * 32 + l16] = f2bf(p[r]);

        // y = P @ v (K=16 padded to 32; pad-P is zero)
        bf16x8 pa = *(const bf16x8*)&Ps[lw * 512 + l16 * 32 + quad * 8];
        #pragma unroll
        for (int nt = 0; nt < 4; ++nt) {
            f32x4 y = {};
            bf16x8 bv = *(const bf16x8*)&vts[(nt * 16 + l16) * 80 + t0 + quad * 8];
            y = __builtin_amdgcn_mfma_f32_16x16x32_bf16(pa, bv, y, 0, 0, 0);
            #pragma unroll
            for (int r = 0; r < 4; ++r)
                XH[(size_t)(m0 + set * 64 + t0 + quad * 4 + r) * 512 + head * 64 + nt * 16 + l16] = f2bf(y[r]);
        }
    }
}

// ---- K3: out = XH @ WP1^T + G[win], 128x128 block, wave 64x64 -------------
// grid (392, 4), XCD-remapped; counted-vmcnt dbuf (vmcnt(8)).
__global__ void __launch_bounds__(256, 2) k_gemm_proj(const unsigned short* __restrict__ XH,
                                                      const unsigned short* __restrict__ WP1,
                                                      const float* __restrict__ G,
                                                      float* __restrict__ out) {
    __shared__ __align__(16) char smem[65536];   // 2 x (A 16KB | B 16KB)

    const int wave = threadIdx.x >> 6, lane = threadIdx.x & 63;
    const int quad = lane >> 4, l16 = lane & 15;

    // bijective XCD remap (1568 = 8*196)
    int id = blockIdx.y * 392 + blockIdx.x;
    int s  = id >> 3;
    int xb = (id & 7) * 49 + (s >> 2);
    int yb = s & 3;
    const int m0 = xb * 128, n0 = yb * 128;
    const int wm = (wave >> 1) * 64;   // wave row offset (2x2 wave grid)
    const int wn = (wave & 1) * 64;    // wave col offset

    int aofs[4], bofs[4];
    #pragma unroll
    for (int i = 0; i < 4; ++i) {
        int u = (wave * 4 + i) * 64 + lane;   // unit 0..1023
        int n = u >> 3;                        // row 0..127
        int gu = (lane & 7) ^ (n & 7);
        aofs[i] = (m0 + n) * 512 + gu * 8;
        bofs[i] = (n0 + n) * 512 + gu * 8;
    }

    unsigned short* const bufA[2] = { (unsigned short*)smem,
                                      (unsigned short*)(smem + 32768) };
    unsigned short* const bufB[2] = { (unsigned short*)(smem + 16384),
                                      (unsigned short*)(smem + 32768 + 16384) };

    f32x4 acc[4][4] = {};
    const int sx = l16 & 7;

    // prologue: stage chunk 0 -> buf0 (8 gl2lds/wave)
    #pragma unroll
    for (int i = 0; i < 4; ++i) {
        gl2lds16(XH + aofs[i], bufA[0] + (wave * 4 + i) * 512);
        gl2lds16(WP1 + bofs[i], bufB[0] + (wave * 4 + i) * 512);
    }

    #pragma unroll
    for (int ch = 0; ch < 8; ++ch) {
        if (ch < 7) {
            unsigned short* An = bufA[(ch + 1) & 1];
            unsigned short* Bn = bufB[(ch + 1) & 1];
            #pragma unroll
            for (int i = 0; i < 4; ++i) {
                gl2lds16(XH + aofs[i] + (ch + 1) * 64, An + (wave * 4 + i) * 512);
                gl2lds16(WP1 + bofs[i] + (ch + 1) * 64, Bn + (wave * 4 + i) * 512);
            }
        }
        if (ch < 7) asm volatile("s_waitcnt vmcnt(8)" ::: "memory");
        else        asm volatile("s_waitcnt vmcnt(0)" ::: "memory");
        __builtin_amdgcn_s_barrier();

        unsigned short* As = bufA[ch & 1];
        unsigned short* Bs = bufB[ch & 1];
        #pragma unroll
        for (int kk = 0; kk < 2; ++kk) {
            int su = ((kk * 4 + quad) ^ sx) * 8;
            bf16x8 a[4], b[4];
            #pragma unroll
            for (int mf = 0; mf < 4; ++mf)
                a[mf] = *(const bf16x8*)&As[(wm + mf * 16 + l16) * 64 + su];
            #pragma unroll
            for (int j = 0; j < 4; ++j)
                b[j] = *(const bf16x8*)&Bs[(wn + j * 16 + l16) * 64 + su];
            #pragma unroll
            for (int mf = 0; mf < 4; ++mf)
                #pragma unroll
                for (int j = 0; j < 4; ++j)
                    acc[mf][j] = __builtin_amdgcn_mfma_f32_16x16x32_bf16(a[mf], b[j], acc[mf][j], 0, 0, 0);
        }
        asm volatile("s_waitcnt lgkmcnt(0)" ::: "memory");
        __builtin_amdgcn_s_barrier();
    }

    #pragma unroll
    for (int mf = 0; mf < 4; ++mf) {
        #pragma unroll
        for (int r = 0; r < 4; ++r) {
            int tl  = wm + mf * 16 + quad * 4 + r;   // 0..127
            int gt  = m0 + tl;                        // global token
            int win = gt >> 4, tw = gt & 15;
            int bb = win / 196, rem = win % 196;
            int wh = rem / 14, ww = rem % 14;
            int orow = (bb * 56 + wh * 4 + (tw >> 2)) * 56 + ww * 4 + (tw & 3);
            #pragma unroll
            for (int j = 0; j < 4; ++j) {
                int ncol = n0 + wn + j * 16 + l16;
                out[(size_t)orow * 512 + ncol] = acc[mf][j][r] + G[(size_t)win * 512 + ncol];
            }
        }
    }
}

// ---------------------------------------------------------------------------
extern "C" void kernel_launch(void* const* d_in, const int* in_sizes, int n_in,
                              void* d_out, int out_size, void* d_ws, size_t ws_size,
                              hipStream_t stream) {
    const float* x      = (const float*)d_in[0];
    const float* wqkv_h = (const float*)d_in[1];
    const float* wqkv_l = (const float*)d_in[2];
    const float* wproj  = (const float*)d_in[3];
    const float* bproj  = (const float*)d_in[4];
    float* out = (float*)d_out;

    char* ws = (char*)d_ws;
    unsigned short* WH   = (unsigned short*)(ws + 0);         // 1536*512 bf16
    unsigned short* WLV  = (unsigned short*)(ws + 1572864);   // 512*512
    unsigned short* WP1  = (unsigned short*)(ws + 2097152);   // 512*512
    unsigned short* WP2  = (unsigned short*)(ws + 2621440);   // 512*512
    unsigned short* XW   = (unsigned short*)(ws + 3145728);   // 50176*512
    unsigned short* XAVG = (unsigned short*)(ws + 54525952);  // 3136*512
    unsigned short* VL   = (unsigned short*)(ws + 57737216);  // 3136*512
    float*          G    = (float*)(ws + 60948480);           // 3136*512 f32
    unsigned short* XH   = (unsigned short*)(ws + 67371008);  // 50176*512

    k_prep_weights<<<dim3(6144), dim3(256), 0, stream>>>(wqkv_h, wqkv_l, wproj, WH, WLV, WP1, WP2);
    k_window_pool<<<dim3(1568), dim3(256), 0, stream>>>(x, XW, XAVG);
    k_gemm512<2><<<dim3(49, 16), dim3(256), 0, stream>>>(XAVG, WLV, VL, (float*)nullptr, (const float*)nullptr);
    k_gemm512<2><<<dim3(49, 16), dim3(256), 0, stream>>>(VL, WP2, (unsigned short*)nullptr, G, bproj);
    k_fused<<<dim3(196, 8), dim3(512), 0, stream>>>(XW, WH, XH);
    k_gemm_proj<<<dim3(392, 4), dim3(256), 0, stream>>>(XH, WP1, G, out);
}